// Round 3
// baseline (12520.364 us; speedup 1.0000x reference)
//
#include <hip/hip_runtime.h>
#include <math.h>

#define T_LEN 512
#define NB    32
#define EMB_  41
#define IN0_  42
#define HID_  800
#define G4_   3200
#define IN1_  1600
#define NU    20
#define NCH   100   // blocks per direction

typedef unsigned short u16;
typedef unsigned int   u32;
typedef unsigned long long u64;
typedef __attribute__((ext_vector_type(8))) short short8;
typedef __attribute__((ext_vector_type(4))) float f32x4;

__device__ __forceinline__ float bf2f(u16 v) {
    union { u32 u; float f; } c; c.u = ((u32)v) << 16; return c.f;
}
__device__ __forceinline__ u16 f2bf(float f) {
    union { float f; u32 u; } c; c.f = f;
    u32 r = (c.u + 0x7fffu + ((c.u >> 16) & 1u)) >> 16;
    return (u16)r;
}
__device__ __forceinline__ short cvt_hl(float v, int hl) {
    u16 hi = f2bf(v);
    return hl ? (short)f2bf(v - bf2f(hi)) : (short)hi;
}
__device__ __forceinline__ f32x4 mfma16(short8 a, short8 b, f32x4 c) {
    return __builtin_amdgcn_mfma_f32_16x16x32_bf16(a, b, c, 0, 0, 0);
}
__device__ __forceinline__ void astore(u64* p, u64 v) {
    __hip_atomic_store(p, v, __ATOMIC_RELAXED, __HIP_MEMORY_SCOPE_AGENT);
}
__device__ __forceinline__ int afload(const int* p) {
    return __hip_atomic_load(p, __ATOMIC_RELAXED, __HIP_MEMORY_SCOPE_AGENT);
}
__device__ __forceinline__ void afstore(int* p, int v) {
    __hip_atomic_store(p, v, __ATOMIC_RELAXED, __HIP_MEMORY_SCOPE_AGENT);
}

// Structure (round-3): 512 threads/block = 4 COMPUTE waves (tid<256, the proven
// round-1 recurrent chain) + 4 X-WAVES (tid>=256) that compute the h-independent
// input-GEMM for step s+1 into a 2-slot LDS ring, concurrently on the same CU.
// X-waves never poll (their inputs are previous-dispatch / host data); ordering
// of the LDS ring is provided entirely by the existing per-step barriers:
//   x writes slot (s+1)&1 at step s (pre-sync A); compute reads slot s&1
//   between sync B and C. All write/read pairs are separated by >=1 barrier.
// h exchange: unchanged from round-1 (per-timestep write-once rings, agent-scope
// atomic producer stores + vmcnt-draining barrier + flag; plain staged consumer
// loads, L2-shared per XCD).

// ---------------- Layer 0 ----------------
__global__ __launch_bounds__(512, 1)
void lstm0_persist(const float* __restrict__ seq, const float* __restrict__ wih0,
                   const float* __restrict__ whh0, const float* __restrict__ bias,
                   u16* __restrict__ h0f, int* __restrict__ flags)
{
    __shared__ __align__(16) float part[2048];          // 8 KB
    __shared__ __align__(16) u16 stageB[25600];         // 51.2 KB h-slab stage
    __shared__ __align__(16) float w0l[32*48];          // 6 KB (x-waves)
    __shared__ __align__(16) float xsl[2][32*48];       // 12 KB (x-waves)
    __shared__ __align__(16) float xw0[2][1024];        // 8 KB xw ring (x->compute)
    __shared__ u16 hpk[NB*8];
    const int tid = threadIdx.x;
    const int d = blockIdx.x / NCH, ch = blockIdx.x % NCH;
    const bool comp = tid < 256;
    const int w = tid >> 6, l = tid & 63;        // compute-wave mapping
    const int p = w & 1, hl = w >> 1;
    const int xt = tid & 255;                    // x-role mapping
    const int xju = xt >> 5, xb = xt & 31;
    int* myflags = flags + d*128;                // packed 4B flags

    short8 wreg[25];
    float biasr[4], wpos[4];
    if (comp) {
        const int m = l & 15, g = p*2 + (m>>3), j = ch*8 + (m&7);
        const float* base = whh0 + ((size_t)(d*G4_ + g*HID_ + j))*HID_ + (l>>4)*8;
#pragma unroll
        for (int kc = 0; kc < 25; ++kc) {
            float4 f0 = *(const float4*)(base + kc*32);
            float4 f1 = *(const float4*)(base + kc*32 + 4);
            short8 v;
            v[0]=cvt_hl(f0.x,hl); v[1]=cvt_hl(f0.y,hl); v[2]=cvt_hl(f0.z,hl); v[3]=cvt_hl(f0.w,hl);
            v[4]=cvt_hl(f1.x,hl); v[5]=cvt_hl(f1.y,hl); v[6]=cvt_hl(f1.z,hl); v[7]=cvt_hl(f1.w,hl);
            wreg[kc] = v;
        }
    } else {
        for (int idx = xt; idx < 32*EMB_; idx += 256) {
            int r = idx / EMB_, k = idx % EMB_;
            int ju_ = r >> 2, g = r & 3;
            w0l[r*48 + k] = wih0[((size_t)(d*G4_ + g*HID_ + ch*8 + ju_))*IN0_ + k];
        }
#pragma unroll
        for (int g = 0; g < 4; ++g) {
            biasr[g] = bias[d*G4_ + g*HID_ + ch*8 + xju];
            wpos[g]  = wih0[((size_t)(d*G4_ + g*HID_ + ch*8 + xju))*IN0_ + EMB_];
        }
        const int t0 = d ? (T_LEN-1) : 0;
        const int t1 = d ? (T_LEN-2) : 1;
        for (int idx = xt; idx < 32*EMB_; idx += 256) {
            xsl[0][(idx/EMB_)*48 + idx%EMB_] = seq[(size_t)t0*(NB*EMB_) + idx];
            xsl[1][(idx/EMB_)*48 + idx%EMB_] = seq[(size_t)t1*(NB*EMB_) + idx];
        }
    }
    const int ju = tid >> 5, b = tid & 31;       // gate mapping (comp)
    const int nt = b >> 4, n = b & 15;
    float creg = 0.f;
    __syncthreads();    // preamble: w0l + xsl[0..1] visible to x dot

    if (!comp) {        // preamble: xw for step 0
        const int t0 = d ? (T_LEN-1) : 0;
        const float* wr = &w0l[xju*4*48];
        const float* xr = &xsl[0][xb*48];
        float dt[4] = {0.f,0.f,0.f,0.f};
#pragma unroll
        for (int k4 = 0; k4 < 40; k4 += 4) {
            float4 xk = *(const float4*)(xr + k4);
#pragma unroll
            for (int g = 0; g < 4; ++g) {
                float4 wv = *(const float4*)(wr + g*48 + k4);
                dt[g] += wv.x*xk.x + wv.y*xk.y + wv.z*xk.z + wv.w*xk.w;
            }
        }
        float xk = xr[40];
#pragma unroll
        for (int g = 0; g < 4; ++g) dt[g] += wr[g*48+40]*xk;
        *(float4*)&xw0[0][(xju*32+xb)*4] = make_float4(
            dt[0]+biasr[0]+(float)t0*wpos[0], dt[1]+biasr[1]+(float)t0*wpos[1],
            dt[2]+biasr[2]+(float)t0*wpos[2], dt[3]+biasr[3]+(float)t0*wpos[3]);
    }

    for (int s = 0; s < T_LEN; ++s) {
        const int t = d ? (T_LEN-1-s) : s;
        if (comp) {
            if (s > 0 && tid < NCH)
                while (afload(myflags + tid) < s) __builtin_amdgcn_s_sleep(1);
        } else {
            const int sx = s + 1;
            if (sx < T_LEN) {   // xw for step s+1 from xsl staged at s-1
                const int tx = d ? (T_LEN-1-sx) : sx;
                const float* wr = &w0l[xju*4*48];
                const float* xr = &xsl[sx&1][xb*48];
                float dt[4] = {0.f,0.f,0.f,0.f};
#pragma unroll
                for (int k4 = 0; k4 < 40; k4 += 4) {
                    float4 xk = *(const float4*)(xr + k4);
#pragma unroll
                    for (int g = 0; g < 4; ++g) {
                        float4 wv = *(const float4*)(wr + g*48 + k4);
                        dt[g] += wv.x*xk.x + wv.y*xk.y + wv.z*xk.z + wv.w*xk.w;
                    }
                }
                float xk = xr[40];
#pragma unroll
                for (int g = 0; g < 4; ++g) dt[g] += wr[g*48+40]*xk;
                *(float4*)&xw0[sx&1][(xju*32+xb)*4] = make_float4(
                    dt[0]+biasr[0]+(float)tx*wpos[0], dt[1]+biasr[1]+(float)tx*wpos[1],
                    dt[2]+biasr[2]+(float)tx*wpos[2], dt[3]+biasr[3]+(float)tx*wpos[3]);
            }
            if (s + 2 < T_LEN) {   // stage x(t(s+2)) for next step's dot
                const int t2 = d ? (T_LEN-1-(s+2)) : (s+2);
                for (int idx = xt; idx < 32*EMB_; idx += 256)
                    xsl[s&1][(idx/EMB_)*48 + idx%EMB_] = seq[(size_t)t2*(NB*EMB_) + idx];
            }
        }
        __syncthreads();   // A

        if (comp) {
            if (s == 0) {
#pragma unroll
                for (int q = 0; q < 25; ++q) ((u64*)stageB)[tid + q*256] = 0ull;
            } else {
                const int tprev = d ? (T_LEN - s) : (s - 1);
                const u64* src = (const u64*)(h0f + (size_t)tprev*51200) + d*6400;
                u64 tmp[25];
#pragma unroll
                for (int q = 0; q < 25; ++q) tmp[q] = src[tid + q*256];
#pragma unroll
                for (int q = 0; q < 25; ++q) ((u64*)stageB)[tid + q*256] = tmp[q];
            }
        }
        __syncthreads();   // B

        if (comp) {
            f32x4 acc0 = {0.f,0.f,0.f,0.f}, acc1 = {0.f,0.f,0.f,0.f};
#pragma unroll 5
            for (int kc = 0; kc < 25; ++kc) {
                short8 b0 = *(const short8*)(stageB + kc*1024 + l*8);
                short8 b1 = *(const short8*)(stageB + kc*1024 + 512 + l*8);
                acc0 = mfma16(wreg[kc], b0, acc0);
                acc1 = mfma16(wreg[kc], b1, acc1);
            }
            const int mrow = (l>>4)*4, nn = l & 15;
#pragma unroll
            for (int r = 0; r < 4; ++r) {
                part[(((p*2+hl)*2 + 0)*16 + mrow + r)*16 + nn] = acc0[r];
                part[(((p*2+hl)*2 + 1)*16 + mrow + r)*16 + nn] = acc1[r];
            }
        }
        __syncthreads();   // C

        if (comp) {
            float4 xwv = *(const float4*)&xw0[s&1][(ju*32+b)*4];
            float xv[4] = {xwv.x, xwv.y, xwv.z, xwv.w};
            float v[4];
#pragma unroll
            for (int g = 0; g < 4; ++g) {
                const int pp = g >> 1, m = (g & 1)*8 + ju;
                v[g] = part[(((pp*2+0)*2 + nt)*16 + m)*16 + n]
                     + part[(((pp*2+1)*2 + nt)*16 + m)*16 + n] + xv[g];
            }
            float ig = 1.f/(1.f + expf(-v[0]));
            float fg = 1.f/(1.f + expf(-v[1]));
            float gg = tanhf(v[2]);
            float og = 1.f/(1.f + expf(-v[3]));
            creg = fg * creg + ig * gg;
            hpk[b*8 + ju] = f2bf(og * tanhf(creg));
        }
        __syncthreads();   // D

        if (comp && tid < 64) {
            const int bb = tid >> 1, half = tid & 1;
            const u16* hp = &hpk[bb*8 + half*4];
            u64 pk = (u64)hp[0] | ((u64)hp[1]<<16) | ((u64)hp[2]<<32) | ((u64)hp[3]<<48);
            const int ntb = bb >> 4, llb = ((ch&3)<<4) | (bb&15);
            const int xoff = ((d*25 + (ch>>2))*2 + ntb)*128 + llb*2 + half;
            astore((u64*)(h0f + (size_t)t*51200) + xoff, pk);
        }
        __syncthreads();   // E: drains vmcnt -> h at coherence point
        if (tid == 0) afstore(myflags + ch, s+1);
    }
}

// ---------------- Layer 1 ----------------
__global__ __launch_bounds__(512, 1)
void lstm1_persist(const float* __restrict__ wih1, const float* __restrict__ whh1,
                   const float* __restrict__ bias, const float* __restrict__ lin_w,
                   const u16* __restrict__ h0f, u16* __restrict__ h1f,
                   int* __restrict__ flags, float* __restrict__ logits)
{
    __shared__ __align__(16) u16 stageB[25600];         // 51.2 KB
    __shared__ __align__(16) float part[2048];          // 8 KB
    __shared__ __align__(16) float xw1[2][2048];        // 16 KB xw ring (x->compute)
    __shared__ u16 hpk[NB*8];
    const int tid = threadIdx.x;
    const int d = blockIdx.x / NCH, ch = blockIdx.x % NCH;
    const bool comp = tid < 256;
    const int w = tid >> 6, l = tid & 63;        // compute mapping
    const int p = w & 1, hl = w >> 1;
    const int xt = tid & 255;                    // x mapping (tid>=256)
    const int xw_ = xt >> 6, xl = xt & 63;
    const int xp = xw_ & 1, xhl = xw_ >> 1;
    int* myflags = flags + d*128;

    short8 wreg[25];   // comp: whh1 hi/lo frags;  x: wih1 hi frags
    if (comp) {
        const int m = l & 15, g = p*2 + (m>>3), j = ch*8 + (m&7);
        const float* base = whh1 + ((size_t)(d*G4_ + g*HID_ + j))*HID_ + (l>>4)*8;
#pragma unroll
        for (int kc = 0; kc < 25; ++kc) {
            float4 f0 = *(const float4*)(base + kc*32);
            float4 f1 = *(const float4*)(base + kc*32 + 4);
            short8 v;
            v[0]=cvt_hl(f0.x,hl); v[1]=cvt_hl(f0.y,hl); v[2]=cvt_hl(f0.z,hl); v[3]=cvt_hl(f0.w,hl);
            v[4]=cvt_hl(f1.x,hl); v[5]=cvt_hl(f1.y,hl); v[6]=cvt_hl(f1.z,hl); v[7]=cvt_hl(f1.w,hl);
            wreg[kc] = v;
        }
    } else {
        const int m = xl & 15, g = xp*2 + (m>>3), jj = ch*8 + (m&7);
#pragma unroll
        for (int kc = 0; kc < 25; ++kc) {
            const int idx = xhl*25 + kc;
            const float* base = wih1 + ((size_t)(d*G4_ + g*HID_ + jj))*IN1_ + idx*32 + (xl>>4)*8;
            float4 f0 = *(const float4*)base;
            float4 f1 = *(const float4*)(base + 4);
            short8 v;
            v[0]=(short)f2bf(f0.x); v[1]=(short)f2bf(f0.y); v[2]=(short)f2bf(f0.z); v[3]=(short)f2bf(f0.w);
            v[4]=(short)f2bf(f1.x); v[5]=(short)f2bf(f1.y); v[6]=(short)f2bf(f1.z); v[7]=(short)f2bf(f1.w);
            wreg[kc] = v;
        }
    }
    // logit-owner constants (compute-side threads only: lo < 640 => tid < 224)
    const int ol = tid >> 5, ln = tid & 31;
    const int lo = ch*7 + ol;
    const bool lown = comp && (ol < 7) && (lo < NB*NU);
    int lofs = 0;
    float wlin[25];
    if (lown) {
        const int bb = lo / NU, uu = lo % NU;
        lofs = (bb >> 4)*512 + ((((ln >> 3) << 4) | (bb & 15)))*8 + (ln & 7);
        const float* wrow = lin_w + (size_t)uu*IN1_ + d*HID_ + ln;
#pragma unroll
        for (int i = 0; i < 25; ++i) wlin[i] = wrow[i*32];
    }
    const int ju = tid >> 5, b = tid & 31;
    const int j = ch*8 + ju;
    const int nt = b >> 4, n = b & 15;
    float biasr[4];
    if (comp) {
#pragma unroll
        for (int g = 0; g < 4; ++g) biasr[g] = bias[d*G4_ + g*HID_ + j];
    }
    float creg = 0.f;

    if (!comp) {    // preamble: xw for step 0 (h0f = previous dispatch, no poll)
        const int t1 = d ? (T_LEN-1) : 0;
        const u16* xb0 = h0f + (size_t)t1*51200;
        f32x4 a0 = {0.f,0.f,0.f,0.f}, a1 = {0.f,0.f,0.f,0.f};
#pragma unroll 5
        for (int kc = 0; kc < 25; ++kc) {
            const int idx = xhl*25 + kc;
            short8 b0 = *(const short8*)(xb0 + idx*1024 + xl*8);
            short8 b1 = *(const short8*)(xb0 + idx*1024 + 512 + xl*8);
            a0 = mfma16(wreg[kc], b0, a0);
            a1 = mfma16(wreg[kc], b1, a1);
        }
#pragma unroll
        for (int r = 0; r < 4; ++r) {
            xw1[0][((xp*2+xhl)*2 + 0)*256 + xl*4 + r] = a0[r];
            xw1[0][((xp*2+xhl)*2 + 1)*256 + xl*4 + r] = a1[r];
        }
    }

    for (int s = 0; s < T_LEN; ++s) {
        const int t = d ? (T_LEN-1-s) : s;
        if (comp) {
            if (s > 0 && tid < NCH)
                while (afload(myflags + tid) < s) __builtin_amdgcn_s_sleep(1);
        } else if (s + 1 < T_LEN) {   // xw for step s+1
            const int sx = s + 1;
            const int t1 = d ? (T_LEN-1-sx) : sx;
            const u16* xb0 = h0f + (size_t)t1*51200;
            f32x4 a0 = {0.f,0.f,0.f,0.f}, a1 = {0.f,0.f,0.f,0.f};
#pragma unroll 5
            for (int kc = 0; kc < 25; ++kc) {
                const int idx = xhl*25 + kc;
                short8 b0 = *(const short8*)(xb0 + idx*1024 + xl*8);
                short8 b1 = *(const short8*)(xb0 + idx*1024 + 512 + xl*8);
                a0 = mfma16(wreg[kc], b0, a0);
                a1 = mfma16(wreg[kc], b1, a1);
            }
#pragma unroll
            for (int r = 0; r < 4; ++r) {
                xw1[sx&1][((xp*2+xhl)*2 + 0)*256 + xl*4 + r] = a0[r];
                xw1[sx&1][((xp*2+xhl)*2 + 1)*256 + xl*4 + r] = a1[r];
            }
        }
        __syncthreads();   // A

        if (comp) {
            if (s == 0) {
#pragma unroll
                for (int q = 0; q < 25; ++q) ((u64*)stageB)[tid + q*256] = 0ull;
            } else {
                const int tprev = d ? (T_LEN - s) : (s - 1);
                const u64* src = (const u64*)(h1f + (size_t)tprev*51200) + d*6400;
                u64 tmp[25];
#pragma unroll
                for (int q = 0; q < 25; ++q) tmp[q] = src[tid + q*256];
#pragma unroll
                for (int q = 0; q < 25; ++q) ((u64*)stageB)[tid + q*256] = tmp[q];
            }
        }
        __syncthreads();   // B

        if (comp) {
            f32x4 acc0, acc1;    // init from the x-wave ring (includes x-GEMM sum)
#pragma unroll
            for (int r = 0; r < 4; ++r) {
                acc0[r] = xw1[s&1][((p*2+hl)*2 + 0)*256 + l*4 + r];
                acc1[r] = xw1[s&1][((p*2+hl)*2 + 1)*256 + l*4 + r];
            }
#pragma unroll 5
            for (int kc = 0; kc < 25; ++kc) {
                short8 b0 = *(const short8*)(stageB + kc*1024 + l*8);
                short8 b1 = *(const short8*)(stageB + kc*1024 + 512 + l*8);
                acc0 = mfma16(wreg[kc], b0, acc0);
                acc1 = mfma16(wreg[kc], b1, acc1);
            }
            const int mrow = (l>>4)*4, nn = l & 15;
#pragma unroll
            for (int r = 0; r < 4; ++r) {
                part[(((p*2+hl)*2 + 0)*16 + mrow + r)*16 + nn] = acc0[r];
                part[(((p*2+hl)*2 + 1)*16 + mrow + r)*16 + nn] = acc1[r];
            }
        }
        __syncthreads();   // C

        if (comp) {
            float v[4];
#pragma unroll
            for (int g = 0; g < 4; ++g) {
                const int pp = g >> 1, m = (g & 1)*8 + ju;
                v[g] = part[(((pp*2+0)*2 + nt)*16 + m)*16 + n]
                     + part[(((pp*2+1)*2 + nt)*16 + m)*16 + n] + biasr[g];
            }
            float ig = 1.f/(1.f + expf(-v[0]));
            float fg = 1.f/(1.f + expf(-v[1]));
            float gg = tanhf(v[2]);
            float og = 1.f/(1.f + expf(-v[3]));
            creg = fg * creg + ig * gg;
            hpk[b*8 + ju] = f2bf(og * tanhf(creg));
        }
        __syncthreads();   // D

        if (comp && tid < 64) {
            const int bb = tid >> 1, half = tid & 1;
            const u16* hp = &hpk[bb*8 + half*4];
            u64 pk = (u64)hp[0] | ((u64)hp[1]<<16) | ((u64)hp[2]<<32) | ((u64)hp[3]<<48);
            const int ntb = bb >> 4, llb = ((ch&3)<<4) | (bb&15);
            const int xoff = ((d*25 + (ch>>2))*2 + ntb)*128 + llb*2 + half;
            astore((u64*)(h1f + (size_t)t*51200) + xoff, pk);
        }
        __syncthreads();   // E: drains vmcnt
        if (tid == 0) afstore(myflags + ch, s+1);

        // distributed logits for h(tprev) from stageB (valid until next staging)
        if (s > 0 && lown) {
            float sum = 0.f;
#pragma unroll
            for (int i = 0; i < 25; ++i)
                sum += bf2f(stageB[i*1024 + lofs]) * wlin[i];
#pragma unroll
            for (int off2 = 16; off2; off2 >>= 1) sum += __shfl_down(sum, off2, 32);
            if (ln == 0) {
                const int tprev = d ? (T_LEN - s) : (s - 1);
                logits[((size_t)d*T_LEN + tprev)*640 + lo] = sum;
            }
        }
    }
    // tail: logits for the final h
    if (tid < NCH)
        while (afload(myflags + tid) < T_LEN) __builtin_amdgcn_s_sleep(1);
    __syncthreads();
    if (comp) {
        const int tlast = d ? 0 : (T_LEN - 1);
        const u64* src = (const u64*)(h1f + (size_t)tlast*51200) + d*6400;
        u64 tmp[25];
#pragma unroll
        for (int q = 0; q < 25; ++q) tmp[q] = src[tid + q*256];
#pragma unroll
        for (int q = 0; q < 25; ++q) ((u64*)stageB)[tid + q*256] = tmp[q];
    }
    __syncthreads();
    if (lown) {
        float sum = 0.f;
#pragma unroll
        for (int i = 0; i < 25; ++i)
            sum += bf2f(stageB[i*1024 + lofs]) * wlin[i];
#pragma unroll
        for (int off2 = 16; off2; off2 >>= 1) sum += __shfl_down(sum, off2, 32);
        if (ln == 0) {
            const int tprev = d ? 0 : (T_LEN - 1);
            logits[((size_t)d*T_LEN + tprev)*640 + lo] = sum;
        }
    }
}

// ---- sum dirs + lin_b -> softmax -> alphabet sin/cos mix; store (cosP, sinP) ----
__global__ __launch_bounds__(256)
void epilogue(const float* __restrict__ logits, const float* __restrict__ lin_b,
              const float* __restrict__ alphabet, float* __restrict__ cs)
{
    __shared__ float sa[NU*3], ca[NU*3], lb[NU];
    const int tid = threadIdx.x;
    if (tid < NU*3) { float al = alphabet[tid]; sa[tid] = sinf(al); ca[tid] = cosf(al); }
    if (tid < NU) lb[tid] = lin_b[tid];
    __syncthreads();
    const int row = blockIdx.x*256 + tid;   // t*NB + b
    if (row >= T_LEN*NB) return;
    const int t = row >> 5, b = row & 31;
    float lg[NU];
    float m = -1e30f;
#pragma unroll 4
    for (int u = 0; u < NU; ++u) {
        lg[u] = lb[u] + logits[(size_t)t*640 + b*NU + u]
                      + logits[((size_t)T_LEN + t)*640 + b*NU + u];
        m = fmaxf(m, lg[u]);
    }
    float ssum = 0.f;
#pragma unroll 4
    for (int u = 0; u < NU; ++u) { lg[u] = expf(lg[u] - m); ssum += lg[u]; }
    float inv = 1.f / ssum;
#pragma unroll
    for (int i = 0; i < 3; ++i) {
        float sv = 0.f, cv = 0.f;
#pragma unroll 4
        for (int u = 0; u < NU; ++u) {
            float sw = lg[u] * inv;
            sv += sw * sa[u*3 + i];
            cv += sw * ca[u*3 + i];
        }
        float rinv = rsqrtf(fmaxf(sv*sv + cv*cv, 1e-30f));
        *(float2*)(cs + ((size_t)row*3 + i)*2) = make_float2(cv*rinv, sv*rinv);
    }
}

// ---- sequential chain extension: one lane per molecule ----
__global__ __launch_bounds__(64)
void geometry(const float* __restrict__ cs, float* __restrict__ out)
{
    const int b = threadIdx.x;
    if (b >= NB) return;
    const float blen[3] = {1.329f, 1.459f, 1.525f};
    const float bang[3] = {2.034f, 2.119f, 1.937f};
    float sT[3], cT[3];
#pragma unroll
    for (int i = 0; i < 3; ++i) { sT[i] = sinf(bang[i]); cT[i] = cosf(bang[i]); }

    float Ax=0.f,Ay=0.f,Az=1.f, Bx=0.f,By=1.f,Bz=0.f, Cx=1.f,Cy=0.f,Cz=0.f;
    out[(0*NB + b)*3 + 0] = 0.f; out[(0*NB + b)*3 + 1] = 0.f; out[(0*NB + b)*3 + 2] = 1.f;
    out[(1*NB + b)*3 + 0] = 0.f; out[(1*NB + b)*3 + 1] = 1.f; out[(1*NB + b)*3 + 2] = 0.f;
    out[(2*NB + b)*3 + 0] = 1.f; out[(2*NB + b)*3 + 1] = 0.f; out[(2*NB + b)*3 + 2] = 0.f;

    for (int t = 1; t < T_LEN; ++t) {
        float2 pc[3];
#pragma unroll
        for (int i = 0; i < 3; ++i)
            pc[i] = *(const float2*)(cs + (((size_t)t*NB + b)*3 + i)*2);
#pragma unroll
        for (int i = 0; i < 3; ++i) {
            float R = blen[i];
            float d2x = -R*cT[i], d2y = R*pc[i].x*sT[i], d2z = R*pc[i].y*sT[i];
            float bcx = Cx-Bx, bcy = Cy-By, bcz = Cz-Bz;
            float inv = rsqrtf(bcx*bcx + bcy*bcy + bcz*bcz);
            bcx *= inv; bcy *= inv; bcz *= inv;
            float abx = Bx-Ax, aby = By-Ay, abz = Bz-Az;
            float nx = aby*bcz - abz*bcy;
            float ny = abz*bcx - abx*bcz;
            float nz = abx*bcy - aby*bcx;
            inv = rsqrtf(fmaxf(nx*nx + ny*ny + nz*nz, 1e-30f));
            nx *= inv; ny *= inv; nz *= inv;
            float mx = ny*bcz - nz*bcy;
            float my = nz*bcx - nx*bcz;
            float mz = nx*bcy - ny*bcx;
            float Dx = bcx*d2x + mx*d2y + nx*d2z + Cx;
            float Dy = bcy*d2x + my*d2y + ny*d2z + Cy;
            float Dz = bcz*d2x + mz*d2y + nz*d2z + Cz;
            Ax=Bx; Ay=By; Az=Bz; Bx=Cx; By=Cy; Bz=Cz; Cx=Dx; Cy=Dy; Cz=Dz;
            const int r = 3 + (t-1)*3 + i;
            out[((size_t)r*NB + b)*3 + 0] = Dx;
            out[((size_t)r*NB + b)*3 + 1] = Dy;
            out[((size_t)r*NB + b)*3 + 2] = Dz;
        }
    }
}

extern "C" void kernel_launch(void* const* d_in, const int* in_sizes, int n_in,
                              void* d_out, int out_size, void* d_ws, size_t ws_size,
                              hipStream_t stream)
{
    (void)in_sizes; (void)n_in; (void)out_size; (void)ws_size;
    const float* seq   = (const float*)d_in[0];
    const float* w_ih0 = (const float*)d_in[2];
    const float* w_hh0 = (const float*)d_in[3];
    const float* b0    = (const float*)d_in[4];
    const float* w_ih1 = (const float*)d_in[5];
    const float* w_hh1 = (const float*)d_in[6];
    const float* b1    = (const float*)d_in[7];
    const float* lin_w = (const float*)d_in[8];
    const float* lin_b = (const float*)d_in[9];
    const float* alpha = (const float*)d_in[10];

    // workspace (~107.9 MB)
    char* ws = (char*)d_ws;
    size_t off = 0;
    u16* h0f   = (u16*)(ws + off); off += 52428800ull;   // [t][d][kc25][nt2][lane][i] bf16
    u16* h1f   = (u16*)(ws + off); off += 52428800ull;   // layer-1 per-t ring
    int* flagsL0 = (int*)(ws + off); off += 1024ull;     // 2 dirs x 128 ints
    int* flagsL1 = (int*)(ws + off); off += 1024ull;
    float* logits = (float*)(ws + off); off += 2621440ull;
    float* cs = (float*)(ws + off); off += 393216ull;

    hipMemsetAsync(flagsL0, 0, 2048, stream);   // both flag arrays

    lstm0_persist<<<dim3(2*NCH), dim3(512), 0, stream>>>(seq, w_ih0, w_hh0, b0, h0f, flagsL0);

    lstm1_persist<<<dim3(2*NCH), dim3(512), 0, stream>>>(w_ih1, w_hh1, b1, lin_w, h0f, h1f,
                                                         flagsL1, logits);

    epilogue<<<dim3(64), dim3(256), 0, stream>>>(logits, lin_b, alpha, cs);
    geometry<<<dim3(1), dim3(64), 0, stream>>>(cs, (float*)d_out);
}

// Round 5
// 11442.444 us; speedup vs baseline: 1.0942x; 1.0942x over previous
//
#include <hip/hip_runtime.h>
#include <math.h>

#define T_LEN 512
#define NB    32
#define EMB_  41
#define IN0_  42
#define HID_  800
#define G4_   3200
#define IN1_  1600
#define NU    20
#define NCH   100   // blocks per direction
#define ARR_TGT (4*NCH)   // 4 waves per block release independently

typedef unsigned short u16;
typedef unsigned int   u32;
typedef unsigned long long u64;
typedef __attribute__((ext_vector_type(8))) short short8;
typedef __attribute__((ext_vector_type(4))) float f32x4;

__device__ __forceinline__ float bf2f(u16 v) {
    union { u32 u; float f; } c; c.u = ((u32)v) << 16; return c.f;
}
__device__ __forceinline__ u16 f2bf(float f) {
    union { float f; u32 u; } c; c.f = f;
    u32 r = (c.u + 0x7fffu + ((c.u >> 16) & 1u)) >> 16;
    return (u16)r;
}
__device__ __forceinline__ short cvt_hl(float v, int hl) {
    u16 hi = f2bf(v);
    return hl ? (short)f2bf(v - bf2f(hi)) : (short)hi;
}
__device__ __forceinline__ f32x4 mfma16(short8 a, short8 b, f32x4 c) {
    return __builtin_amdgcn_mfma_f32_16x16x32_bf16(a, b, c, 0, 0, 0);
}
__device__ __forceinline__ void astore32(u32* p, u32 v) {
    __hip_atomic_store(p, v, __ATOMIC_RELAXED, __HIP_MEMORY_SCOPE_AGENT);
}
__device__ __forceinline__ int afload(const int* p) {
    return __hip_atomic_load(p, __ATOMIC_RELAXED, __HIP_MEMORY_SCOPE_AGENT);
}
__device__ __forceinline__ void aadd(int* p) {
    __hip_atomic_fetch_add(p, 1, __ATOMIC_RELAXED, __HIP_MEMORY_SCOPE_AGENT);
}

// Sync topology: per-(dir,step) ARRIVAL COUNTER.
//  * Producer waves each store their own h chunk (u32 agent-scope atomic
//    stores into the per-timestep write-once ring), drain their OWN vmcnt,
//    then lane0 does fetch_add(arr[d][s]).  No block barrier on release.
//  * Consumers poll the single counter (all lanes, one address) until 400,
//    then plain-load the slab (first touch on this XCD is post-release ->
//    L2 fill pulls fresh LLC data; ~25 blocks/XCD share it).
//  * The poll is a full-block rendezvous (counter includes this block's own
//    4 waves), so s_barrier instances can never be concurrently mismatched,
//    and all cross-step LDS reuse (stageB/part/xsl) is ordered by
//    poll + the two remaining barriers.
// Only 2 barriers/step remain: B (stage-write -> MFMA-read) and
// C (part-write -> gate-read).

// ---------------- Layer 0: persistent, 200 blocks x 256 threads ----------------
__global__ __launch_bounds__(256, 1)
void lstm0_persist(const float* __restrict__ seq, const float* __restrict__ wih0,
                   const float* __restrict__ whh0, const float* __restrict__ bias,
                   u16* __restrict__ h0f, int* __restrict__ arr)
{
    __shared__ __align__(16) float part[2048];          // 8 KB
    __shared__ __align__(16) u16 stageB[25600];         // 51.2 KB h-slab stage
    __shared__ __align__(16) float w0l[32*48];          // 6 KB
    __shared__ __align__(16) float xsl[2][32*48];       // 12 KB double-buffered
    const int tid = threadIdx.x;
    const int d = blockIdx.x / NCH, ch = blockIdx.x % NCH;
    const int w = tid >> 6, l = tid & 63;
    const int p = w & 1, hl = w >> 1;
    int* myarr = arr + d*512;

    short8 wreg[25];   // whh0 hi/lo A-frags, register-resident
    {
        const int m = l & 15, g = p*2 + (m>>3), j = ch*8 + (m&7);
        const float* base = whh0 + ((size_t)(d*G4_ + g*HID_ + j))*HID_ + (l>>4)*8;
#pragma unroll
        for (int kc = 0; kc < 25; ++kc) {
            float4 f0 = *(const float4*)(base + kc*32);
            float4 f1 = *(const float4*)(base + kc*32 + 4);
            short8 v;
            v[0]=cvt_hl(f0.x,hl); v[1]=cvt_hl(f0.y,hl); v[2]=cvt_hl(f0.z,hl); v[3]=cvt_hl(f0.w,hl);
            v[4]=cvt_hl(f1.x,hl); v[5]=cvt_hl(f1.y,hl); v[6]=cvt_hl(f1.z,hl); v[7]=cvt_hl(f1.w,hl);
            wreg[kc] = v;
        }
    }
    for (int idx = tid; idx < 32*EMB_; idx += 256) {
        int r = idx / EMB_, k = idx % EMB_;
        int ju_ = r >> 2, g = r & 3;
        w0l[r*48 + k] = wih0[((size_t)(d*G4_ + g*HID_ + ch*8 + ju_))*IN0_ + k];
    }
    const int ju = tid >> 5, b = tid & 31;
    const int j = ch*8 + ju;
    const int nt = b >> 4, n = b & 15;
    float biasr[4], wpos[4];
#pragma unroll
    for (int g = 0; g < 4; ++g) {
        biasr[g] = bias[d*G4_ + g*HID_ + j];
        wpos[g]  = wih0[((size_t)(d*G4_ + g*HID_ + j))*IN0_ + EMB_];
    }
    float creg = 0.f;
    __syncthreads();

    for (int s = 0; s < T_LEN; ++s) {
        const int t = d ? (T_LEN-1-s) : s;

        // h-independent: stage x(t) into the step-parity slot (pre-poll)
        for (int idx = tid; idx < 32*EMB_; idx += 256)
            xsl[s&1][(idx/EMB_)*48 + idx%EMB_] = seq[(size_t)t*(NB*EMB_) + idx];

        // single-address poll (per wave, all lanes same address)
        if (s > 0)
            while (afload(myarr + (s-1)) < ARR_TGT) __builtin_amdgcn_s_sleep(1);

        // stage the 51.2 KB h-slab of step s-1 (plain loads, L2-shared)
        if (s == 0) {
#pragma unroll
            for (int q = 0; q < 25; ++q) ((u64*)stageB)[tid + q*256] = 0ull;
        } else {
            const int tprev = d ? (T_LEN - s) : (s - 1);
            const u64* src = (const u64*)(h0f + (size_t)tprev*51200) + d*6400;
            u64 tmp[25];
#pragma unroll
            for (int q = 0; q < 25; ++q) tmp[q] = src[tid + q*256];
#pragma unroll
            for (int q = 0; q < 25; ++q) ((u64*)stageB)[tid + q*256] = tmp[q];
        }
        __syncthreads();   // B: stage-write -> MFMA-read

        f32x4 acc0 = {0.f,0.f,0.f,0.f}, acc1 = {0.f,0.f,0.f,0.f};
#pragma unroll 5
        for (int kc = 0; kc < 25; ++kc) {
            short8 b0 = *(const short8*)(stageB + kc*1024 + l*8);
            short8 b1 = *(const short8*)(stageB + kc*1024 + 512 + l*8);
            acc0 = mfma16(wreg[kc], b0, acc0);
            acc1 = mfma16(wreg[kc], b1, acc1);
        }
        {
            const int mrow = (l>>4)*4, nn = l & 15;
#pragma unroll
            for (int r = 0; r < 4; ++r) {
                part[(((p*2+hl)*2 + 0)*16 + mrow + r)*16 + nn] = acc0[r];
                part[(((p*2+hl)*2 + 1)*16 + mrow + r)*16 + nn] = acc1[r];
            }
        }
        __syncthreads();   // C: part-write -> gate-read

        float dot0 = 0.f, dot1 = 0.f, dot2 = 0.f, dot3 = 0.f;
        {
            const float* wr = &w0l[ju*4*48];
            const float* xr = &xsl[s&1][b*48];
#pragma unroll
            for (int k4 = 0; k4 < 40; k4 += 4) {
                float4 xk = *(const float4*)(xr + k4);
                float4 w0 = *(const float4*)(wr + 0*48 + k4);
                float4 w1 = *(const float4*)(wr + 1*48 + k4);
                float4 w2 = *(const float4*)(wr + 2*48 + k4);
                float4 w3 = *(const float4*)(wr + 3*48 + k4);
                dot0 += w0.x*xk.x + w0.y*xk.y + w0.z*xk.z + w0.w*xk.w;
                dot1 += w1.x*xk.x + w1.y*xk.y + w1.z*xk.z + w1.w*xk.w;
                dot2 += w2.x*xk.x + w2.y*xk.y + w2.z*xk.z + w2.w*xk.w;
                dot3 += w3.x*xk.x + w3.y*xk.y + w3.z*xk.z + w3.w*xk.w;
            }
            float xk = xr[40];
            dot0 += wr[0*48+40]*xk; dot1 += wr[1*48+40]*xk;
            dot2 += wr[2*48+40]*xk; dot3 += wr[3*48+40]*xk;
        }
        float v[4] = {dot0, dot1, dot2, dot3};
#pragma unroll
        for (int g = 0; g < 4; ++g) {
            const int pp = g >> 1, m = (g & 1)*8 + ju;
            v[g] += part[(((pp*2+0)*2 + nt)*16 + m)*16 + n]
                  + part[(((pp*2+1)*2 + nt)*16 + m)*16 + n]
                  + biasr[g] + (float)t * wpos[g];
        }
        float ig = 1.f/(1.f + expf(-v[0]));
        float fg = 1.f/(1.f + expf(-v[1]));
        float gg = tanhf(v[2]);
        float og = 1.f/(1.f + expf(-v[3]));
        creg = fg * creg + ig * gg;
        float hval = og * tanhf(creg);

        // wave-autonomous release: lane pairs (l, l|32) pack one u32
        u32 hv = (u32)f2bf(hval);
        u32 ov = (u32)__shfl((int)hv, l | 32);
        if (l < 32) {
            const int ntb = b >> 4, llb = ((ch&3)<<4) | (b&15);
            const int half = w >> 1;
            const u32 xoff = (u32)(((d*25 + (ch>>2))*2 + ntb)*128 + llb*2 + half);
            astore32((u32*)(h0f + (size_t)t*51200) + xoff*2 + (w&1), hv | (ov<<16));
        }
        asm volatile("s_waitcnt vmcnt(0)" ::: "memory");
        if (l == 0) aadd(myarr + s);
    }
}

// ---------------- Layer 1: persistent; fused x-GEMM + distributed final linear ----------------
__global__ __launch_bounds__(256, 1)
void lstm1_persist(const float* __restrict__ wih1, const float* __restrict__ whh1,
                   const float* __restrict__ bias, const float* __restrict__ lin_w,
                   const u16* __restrict__ h0f, u16* __restrict__ h1f,
                   int* __restrict__ arr, float* __restrict__ logits)
{
    __shared__ __align__(16) u16 wihL[2*50*512];        // 100 KB w_ih1 A-frags
    __shared__ __align__(16) u16 stageB[25600];         // 51.2 KB
    __shared__ __align__(16) float part[2048];          // 8 KB
    const int tid = threadIdx.x;
    const int d = blockIdx.x / NCH, ch = blockIdx.x % NCH;
    const int w = tid >> 6, l = tid & 63;
    const int p = w & 1, hl = w >> 1;
    int* myarr = arr + d*512;

    short8 wreg[25];
    {
        const int m = l & 15, g = p*2 + (m>>3), j = ch*8 + (m&7);
        const float* base = whh1 + ((size_t)(d*G4_ + g*HID_ + j))*HID_ + (l>>4)*8;
#pragma unroll
        for (int kc = 0; kc < 25; ++kc) {
            float4 f0 = *(const float4*)(base + kc*32);
            float4 f1 = *(const float4*)(base + kc*32 + 4);
            short8 v;
            v[0]=cvt_hl(f0.x,hl); v[1]=cvt_hl(f0.y,hl); v[2]=cvt_hl(f0.z,hl); v[3]=cvt_hl(f0.w,hl);
            v[4]=cvt_hl(f1.x,hl); v[5]=cvt_hl(f1.y,hl); v[6]=cvt_hl(f1.z,hl); v[7]=cvt_hl(f1.w,hl);
            wreg[kc] = v;
        }
    }
    for (int o = tid; o < 6400; o += 256) {
        int pp = o / 3200, r = o % 3200, kc = r >> 6, ll = r & 63;
        int m = ll & 15, g = pp*2 + (m>>3), jj = ch*8 + (m&7);
        const float* base = wih1 + ((size_t)(d*G4_ + g*HID_ + jj))*IN1_ + kc*32 + (ll>>4)*8;
        float4 f0 = *(const float4*)base;
        float4 f1 = *(const float4*)(base + 4);
        short8 v;
        v[0]=(short)f2bf(f0.x); v[1]=(short)f2bf(f0.y); v[2]=(short)f2bf(f0.z); v[3]=(short)f2bf(f0.w);
        v[4]=(short)f2bf(f1.x); v[5]=(short)f2bf(f1.y); v[6]=(short)f2bf(f1.z); v[7]=(short)f2bf(f1.w);
        *(short8*)&wihL[o*8] = v;
    }
    // logit-owner constants + register-resident lin_w (step-invariant)
    const int ol = tid >> 5, ln = tid & 31;
    const int lo = ch*7 + ol;
    const bool lown = (ol < 7) && (lo < NB*NU);
    int lofs = 0;
    float wlin[25];
    if (lown) {
        const int bb = lo / NU, uu = lo % NU;
        lofs = (bb >> 4)*512 + ((((ln >> 3) << 4) | (bb & 15)))*8 + (ln & 7);
        const float* wrow = lin_w + (size_t)uu*IN1_ + d*HID_ + ln;
#pragma unroll
        for (int i = 0; i < 25; ++i) wlin[i] = wrow[i*32];
    }
    const int ju = tid >> 5, b = tid & 31;
    const int j = ch*8 + ju;
    const int nt = b >> 4, n = b & 15;
    float biasr[4];
#pragma unroll
    for (int g = 0; g < 4; ++g) biasr[g] = bias[d*G4_ + g*HID_ + j];
    float creg = 0.f;
    __syncthreads();

    for (int s = 0; s < T_LEN; ++s) {
        const int t = d ? (T_LEN-1-s) : s;

        // x-part GEMM BEFORE the poll: depends only on h0f (previous dispatch)
        f32x4 acc0 = {0.f,0.f,0.f,0.f}, acc1 = {0.f,0.f,0.f,0.f};
        {
            const u16* xb = h0f + (size_t)t*51200;
#pragma unroll 5
            for (int kc = 0; kc < 25; ++kc) {
                const int idx = hl*25 + kc;
                short8 a  = *(const short8*)&wihL[(p*50 + idx)*512 + l*8];
                short8 b0 = *(const short8*)(xb + idx*1024 + l*8);
                short8 b1 = *(const short8*)(xb + idx*1024 + 512 + l*8);
                acc0 = mfma16(a, b0, acc0);
                acc1 = mfma16(a, b1, acc1);
            }
        }

        if (s > 0)
            while (afload(myarr + (s-1)) < ARR_TGT) __builtin_amdgcn_s_sleep(1);

        if (s == 0) {
#pragma unroll
            for (int q = 0; q < 25; ++q) ((u64*)stageB)[tid + q*256] = 0ull;
        } else {
            const int tprev = d ? (T_LEN - s) : (s - 1);
            const u64* src = (const u64*)(h1f + (size_t)tprev*51200) + d*6400;
            u64 tmp[25];
#pragma unroll
            for (int q = 0; q < 25; ++q) tmp[q] = src[tid + q*256];
#pragma unroll
            for (int q = 0; q < 25; ++q) ((u64*)stageB)[tid + q*256] = tmp[q];
        }
        __syncthreads();   // B

#pragma unroll 5
        for (int kc = 0; kc < 25; ++kc) {
            short8 b0 = *(const short8*)(stageB + kc*1024 + l*8);
            short8 b1 = *(const short8*)(stageB + kc*1024 + 512 + l*8);
            acc0 = mfma16(wreg[kc], b0, acc0);
            acc1 = mfma16(wreg[kc], b1, acc1);
        }
        {
            const int mrow = (l>>4)*4, nn = l & 15;
#pragma unroll
            for (int r = 0; r < 4; ++r) {
                part[(((p*2+hl)*2 + 0)*16 + mrow + r)*16 + nn] = acc0[r];
                part[(((p*2+hl)*2 + 1)*16 + mrow + r)*16 + nn] = acc1[r];
            }
        }
        __syncthreads();   // C

        float v[4];
#pragma unroll
        for (int g = 0; g < 4; ++g) {
            const int pp = g >> 1, m = (g & 1)*8 + ju;
            v[g] = part[(((pp*2+0)*2 + nt)*16 + m)*16 + n]
                 + part[(((pp*2+1)*2 + nt)*16 + m)*16 + n] + biasr[g];
        }
        float ig = 1.f/(1.f + expf(-v[0]));
        float fg = 1.f/(1.f + expf(-v[1]));
        float gg = tanhf(v[2]);
        float og = 1.f/(1.f + expf(-v[3]));
        creg = fg * creg + ig * gg;
        float hval = og * tanhf(creg);

        u32 hv = (u32)f2bf(hval);
        u32 ov = (u32)__shfl((int)hv, l | 32);
        if (l < 32) {
            const int ntb = b >> 4, llb = ((ch&3)<<4) | (b&15);
            const int half = w >> 1;
            const u32 xoff = (u32)(((d*25 + (ch>>2))*2 + ntb)*128 + llb*2 + half);
            astore32((u32*)(h1f + (size_t)t*51200) + xoff*2 + (w&1), hv | (ov<<16));
        }
        asm volatile("s_waitcnt vmcnt(0)" ::: "memory");
        if (l == 0) aadd(myarr + s);

        // distributed logits for h(tprev): plain loads of the L2-warm slab
        if (s > 0 && lown) {
            const int tprev = d ? (T_LEN - s) : (s - 1);
            const u16* hb = h1f + (size_t)tprev*51200 + d*25600;
            float sum = 0.f;
#pragma unroll
            for (int i = 0; i < 25; ++i)
                sum += bf2f(hb[i*1024 + lofs]) * wlin[i];
#pragma unroll
            for (int off2 = 16; off2; off2 >>= 1) sum += __shfl_down(sum, off2, 32);
            if (ln == 0)
                logits[((size_t)d*T_LEN + tprev)*640 + lo] = sum;
        }
    }
    // tail: logits for the final h
    while (afload(myarr + (T_LEN-1)) < ARR_TGT) __builtin_amdgcn_s_sleep(1);
    if (lown) {
        const int tlast = d ? 0 : (T_LEN - 1);
        const u16* hb = h1f + (size_t)tlast*51200 + d*25600;
        float sum = 0.f;
#pragma unroll
        for (int i = 0; i < 25; ++i)
            sum += bf2f(hb[i*1024 + lofs]) * wlin[i];
#pragma unroll
        for (int off2 = 16; off2; off2 >>= 1) sum += __shfl_down(sum, off2, 32);
        if (ln == 0)
            logits[((size_t)d*T_LEN + tlast)*640 + lo] = sum;
    }
}

// ---- sum dirs + lin_b -> softmax -> alphabet sin/cos mix; store (cosP, sinP) ----
__global__ __launch_bounds__(256)
void epilogue(const float* __restrict__ logits, const float* __restrict__ lin_b,
              const float* __restrict__ alphabet, float* __restrict__ cs)
{
    __shared__ float sa[NU*3], ca[NU*3], lb[NU];
    const int tid = threadIdx.x;
    if (tid < NU*3) { float al = alphabet[tid]; sa[tid] = sinf(al); ca[tid] = cosf(al); }
    if (tid < NU) lb[tid] = lin_b[tid];
    __syncthreads();
    const int row = blockIdx.x*256 + tid;   // t*NB + b
    if (row >= T_LEN*NB) return;
    const int t = row >> 5, b = row & 31;
    float lg[NU];
    float m = -1e30f;
#pragma unroll 4
    for (int u = 0; u < NU; ++u) {
        lg[u] = lb[u] + logits[(size_t)t*640 + b*NU + u]
                      + logits[((size_t)T_LEN + t)*640 + b*NU + u];
        m = fmaxf(m, lg[u]);
    }
    float ssum = 0.f;
#pragma unroll 4
    for (int u = 0; u < NU; ++u) { lg[u] = expf(lg[u] - m); ssum += lg[u]; }
    float inv = 1.f / ssum;
#pragma unroll
    for (int i = 0; i < 3; ++i) {
        float sv = 0.f, cv = 0.f;
#pragma unroll 4
        for (int u = 0; u < NU; ++u) {
            float sw = lg[u] * inv;
            sv += sw * sa[u*3 + i];
            cv += sw * ca[u*3 + i];
        }
        float rinv = rsqrtf(fmaxf(sv*sv + cv*cv, 1e-30f));
        *(float2*)(cs + ((size_t)row*3 + i)*2) = make_float2(cv*rinv, sv*rinv);
    }
}

// ---- sequential chain extension: one lane per molecule ----
__global__ __launch_bounds__(64)
void geometry(const float* __restrict__ cs, float* __restrict__ out)
{
    const int b = threadIdx.x;
    if (b >= NB) return;
    const float blen[3] = {1.329f, 1.459f, 1.525f};
    const float bang[3] = {2.034f, 2.119f, 1.937f};
    float sT[3], cT[3];
#pragma unroll
    for (int i = 0; i < 3; ++i) { sT[i] = sinf(bang[i]); cT[i] = cosf(bang[i]); }

    float Ax=0.f,Ay=0.f,Az=1.f, Bx=0.f,By=1.f,Bz=0.f, Cx=1.f,Cy=0.f,Cz=0.f;
    out[(0*NB + b)*3 + 0] = 0.f; out[(0*NB + b)*3 + 1] = 0.f; out[(0*NB + b)*3 + 2] = 1.f;
    out[(1*NB + b)*3 + 0] = 0.f; out[(1*NB + b)*3 + 1] = 1.f; out[(1*NB + b)*3 + 2] = 0.f;
    out[(2*NB + b)*3 + 0] = 1.f; out[(2*NB + b)*3 + 1] = 0.f; out[(2*NB + b)*3 + 2] = 0.f;

    for (int t = 1; t < T_LEN; ++t) {
        float2 pc[3];
#pragma unroll
        for (int i = 0; i < 3; ++i)
            pc[i] = *(const float2*)(cs + (((size_t)t*NB + b)*3 + i)*2);
#pragma unroll
        for (int i = 0; i < 3; ++i) {
            float R = blen[i];
            float d2x = -R*cT[i], d2y = R*pc[i].x*sT[i], d2z = R*pc[i].y*sT[i];
            float bcx = Cx-Bx, bcy = Cy-By, bcz = Cz-Bz;
            float inv = rsqrtf(bcx*bcx + bcy*bcy + bcz*bcz);
            bcx *= inv; bcy *= inv; bcz *= inv;
            float abx = Bx-Ax, aby = By-Ay, abz = Bz-Az;
            float nx = aby*bcz - abz*bcy;
            float ny = abz*bcx - abx*bcz;
            float nz = abx*bcy - aby*bcx;
            inv = rsqrtf(fmaxf(nx*nx + ny*ny + nz*nz, 1e-30f));
            nx *= inv; ny *= inv; nz *= inv;
            float mx = ny*bcz - nz*bcy;
            float my = nz*bcx - nx*bcz;
            float mz = nx*bcy - ny*bcx;
            float Dx = bcx*d2x + mx*d2y + nx*d2z + Cx;
            float Dy = bcy*d2x + my*d2y + ny*d2z + Cy;
            float Dz = bcz*d2x + mz*d2y + nz*d2z + Cz;
            Ax=Bx; Ay=By; Az=Bz; Bx=Cx; By=Cy; Bz=Cz; Cx=Dx; Cy=Dy; Cz=Dz;
            const int r = 3 + (t-1)*3 + i;
            out[((size_t)r*NB + b)*3 + 0] = Dx;
            out[((size_t)r*NB + b)*3 + 1] = Dy;
            out[((size_t)r*NB + b)*3 + 2] = Dz;
        }
    }
}

extern "C" void kernel_launch(void* const* d_in, const int* in_sizes, int n_in,
                              void* d_out, int out_size, void* d_ws, size_t ws_size,
                              hipStream_t stream)
{
    (void)in_sizes; (void)n_in; (void)out_size; (void)ws_size;
    const float* seq   = (const float*)d_in[0];
    const float* w_ih0 = (const float*)d_in[2];
    const float* w_hh0 = (const float*)d_in[3];
    const float* b0    = (const float*)d_in[4];
    const float* w_ih1 = (const float*)d_in[5];
    const float* w_hh1 = (const float*)d_in[6];
    const float* b1    = (const float*)d_in[7];
    const float* lin_w = (const float*)d_in[8];
    const float* lin_b = (const float*)d_in[9];
    const float* alpha = (const float*)d_in[10];

    // workspace (~107.9 MB): two per-timestep h rings + arrival counters
    char* ws = (char*)d_ws;
    size_t off = 0;
    u16* h0f   = (u16*)(ws + off); off += 52428800ull;   // [t][d][kc25][nt2][lane][i] bf16
    u16* h1f   = (u16*)(ws + off); off += 52428800ull;   // layer-1 per-t ring
    int* arrL0 = (int*)(ws + off); off += 4096ull;       // [d][s] arrival counters
    int* arrL1 = (int*)(ws + off); off += 4096ull;
    float* logits = (float*)(ws + off); off += 2621440ull;
    float* cs = (float*)(ws + off); off += 393216ull;

    hipMemsetAsync(arrL0, 0, 8192, stream);   // both counter arrays

    lstm0_persist<<<dim3(2*NCH), dim3(256), 0, stream>>>(seq, w_ih0, w_hh0, b0, h0f, arrL0);

    lstm1_persist<<<dim3(2*NCH), dim3(256), 0, stream>>>(w_ih1, w_hh1, b1, lin_w, h0f, h1f,
                                                         arrL1, logits);

    epilogue<<<dim3(64), dim3(256), 0, stream>>>(logits, lin_b, alpha, cs);
    geometry<<<dim3(1), dim3(64), 0, stream>>>(cs, (float*)d_out);
}

// Round 6
// 9321.128 us; speedup vs baseline: 1.3432x; 1.2276x over previous
//
#include <hip/hip_runtime.h>
#include <math.h>

#define T_LEN 512
#define NB    32
#define EMB_  41
#define IN0_  42
#define HID_  800
#define G4_   3200
#define IN1_  1600
#define NU    20
#define NCH0  50    // layer-0 blocks per direction (j-width 16 via T in {0,1})
#define NCH   100   // layer-1 blocks per direction (unchanged r1 structure)

typedef unsigned short u16;
typedef unsigned int   u32;
typedef unsigned long long u64;
typedef __attribute__((ext_vector_type(8))) short short8;
typedef __attribute__((ext_vector_type(4))) float f32x4;

__device__ __forceinline__ float bf2f(u16 v) {
    union { u32 u; float f; } c; c.u = ((u32)v) << 16; return c.f;
}
__device__ __forceinline__ u16 f2bf(float f) {
    union { float f; u32 u; } c; c.f = f;
    u32 r = (c.u + 0x7fffu + ((c.u >> 16) & 1u)) >> 16;
    return (u16)r;
}
__device__ __forceinline__ short cvt_hl(float v, int hl) {
    u16 hi = f2bf(v);
    return hl ? (short)f2bf(v - bf2f(hi)) : (short)hi;
}
__device__ __forceinline__ f32x4 mfma16(short8 a, short8 b, f32x4 c) {
    return __builtin_amdgcn_mfma_f32_16x16x32_bf16(a, b, c, 0, 0, 0);
}
__device__ __forceinline__ void astore(u64* p, u64 v) {
    __hip_atomic_store(p, v, __ATOMIC_RELAXED, __HIP_MEMORY_SCOPE_AGENT);
}
__device__ __forceinline__ int afload(const int* p) {
    return __hip_atomic_load(p, __ATOMIC_RELAXED, __HIP_MEMORY_SCOPE_AGENT);
}
__device__ __forceinline__ void afstore(int* p, int v) {
    __hip_atomic_store(p, v, __ATOMIC_RELAXED, __HIP_MEMORY_SCOPE_AGENT);
}

// h-exchange (r1-proven): per-timestep write-once rings; producers store h via
// agent-scope atomic u64, a block barrier drains vmcnt, then one flag store per
// block (packed 4B flags). Consumers poll the flags then PLAIN-load the slab
// (first touch post-flag -> L2 fill pulls fresh LLC data, shared per XCD).
// Round-6 change: layer 0 uses 50 blocks/direction, each covering TWO of the
// old 8-j chunks (ch2 = 2*ch + T). h0f slab layout is bit-identical to r1, so
// layer 1 is untouched. Numerics: each (T) accumulator chain is exactly the old
// chunk ch2's chain -> bit-identical results.

// ---------------- Layer 0: persistent, 100 blocks x 256 threads ----------------
__global__ __launch_bounds__(256, 1)
void lstm0_persist(const float* __restrict__ seq, const float* __restrict__ wih0,
                   const float* __restrict__ whh0, const float* __restrict__ bias,
                   u16* __restrict__ h0f, int* __restrict__ flags)
{
    __shared__ __align__(16) float part[4096];          // 16 KB (2 T x 8 tiles)
    __shared__ __align__(16) u16 stageB[25600];         // 51.2 KB h-slab stage
    __shared__ __align__(16) float w0l[64*48];          // 12 KB (16 j x 4 g rows)
    __shared__ __align__(16) float xsl[2][32*48];       // 12 KB double-buffered
    __shared__ u16 hpk[2][NB*8];
    const int tid = threadIdx.x;
    const int d = blockIdx.x / NCH0, ch = blockIdx.x % NCH0;
    const int w = tid >> 6, l = tid & 63;
    const int p = w & 1, hl = w >> 1;
    int* myflags = flags + d*128;      // packed: flag[ch] at 4B stride

    short8 wreg[2][25];   // whh0 hi/lo A-frags for chunks 2ch+0, 2ch+1
    {
        const int m = l & 15, g = p*2 + (m>>3);
#pragma unroll
        for (int T = 0; T < 2; ++T) {
            const int j = (ch*2 + T)*8 + (m&7);
            const float* base = whh0 + ((size_t)(d*G4_ + g*HID_ + j))*HID_ + (l>>4)*8;
#pragma unroll
            for (int kc = 0; kc < 25; ++kc) {
                float4 f0 = *(const float4*)(base + kc*32);
                float4 f1 = *(const float4*)(base + kc*32 + 4);
                short8 v;
                v[0]=cvt_hl(f0.x,hl); v[1]=cvt_hl(f0.y,hl); v[2]=cvt_hl(f0.z,hl); v[3]=cvt_hl(f0.w,hl);
                v[4]=cvt_hl(f1.x,hl); v[5]=cvt_hl(f1.y,hl); v[6]=cvt_hl(f1.z,hl); v[7]=cvt_hl(f1.w,hl);
                wreg[T][kc] = v;
            }
        }
    }
    for (int idx = tid; idx < 64*EMB_; idx += 256) {
        int r = idx / EMB_, k = idx % EMB_;
        int ju_ = r >> 2, g = r & 3;          // ju_ in [0,16)
        w0l[r*48 + k] = wih0[((size_t)(d*G4_ + g*HID_ + ch*16 + ju_))*IN0_ + k];
    }
    const int ju = tid >> 5, b = tid & 31;    // gate mapping: ju in [0,8), x2 via T
    const int nt = b >> 4, n = b & 15;
    float biasr[2][4], wpos[2][4];
#pragma unroll
    for (int T = 0; T < 2; ++T) {
        const int j = ch*16 + T*8 + ju;
#pragma unroll
        for (int g = 0; g < 4; ++g) {
            biasr[T][g] = bias[d*G4_ + g*HID_ + j];
            wpos[T][g]  = wih0[((size_t)(d*G4_ + g*HID_ + j))*IN0_ + EMB_];
        }
    }
    float creg[2] = {0.f, 0.f};
    __syncthreads();

    for (int s = 0; s < T_LEN; ++s) {
        const int t = d ? (T_LEN-1-s) : s;

        // h-independent: stage x(t) (pre-poll)
        for (int idx = tid; idx < 32*EMB_; idx += 256)
            xsl[s&1][(idx/EMB_)*48 + idx%EMB_] = seq[(size_t)t*(NB*EMB_) + idx];

        if (s > 0 && tid < NCH0)
            while (afload(myflags + tid) < s) __builtin_amdgcn_s_sleep(1);
        __syncthreads();

        // stage the 51.2 KB h-slab of step s-1 (plain loads, L2-shared)
        if (s == 0) {
#pragma unroll
            for (int q = 0; q < 25; ++q) ((u64*)stageB)[tid + q*256] = 0ull;
        } else {
            const int tprev = d ? (T_LEN - s) : (s - 1);
            const u64* src = (const u64*)(h0f + (size_t)tprev*51200) + d*6400;
            u64 tmp[25];
#pragma unroll
            for (int q = 0; q < 25; ++q) tmp[q] = src[tid + q*256];
#pragma unroll
            for (int q = 0; q < 25; ++q) ((u64*)stageB)[tid + q*256] = tmp[q];
        }
        __syncthreads();   // B: stage-write -> MFMA-read

        // 4 independent accumulator chains share each LDS B-read
        f32x4 a00 = {0.f,0.f,0.f,0.f}, a01 = {0.f,0.f,0.f,0.f};
        f32x4 a10 = {0.f,0.f,0.f,0.f}, a11 = {0.f,0.f,0.f,0.f};
#pragma unroll
        for (int kc = 0; kc < 25; ++kc) {
            short8 b0 = *(const short8*)(stageB + kc*1024 + l*8);
            short8 b1 = *(const short8*)(stageB + kc*1024 + 512 + l*8);
            a00 = mfma16(wreg[0][kc], b0, a00);
            a01 = mfma16(wreg[0][kc], b1, a01);
            a10 = mfma16(wreg[1][kc], b0, a10);
            a11 = mfma16(wreg[1][kc], b1, a11);
        }
        {
            const int mrow = (l>>4)*4, nn = l & 15;
#pragma unroll
            for (int r = 0; r < 4; ++r) {
                part[((0*8 + (p*2+hl)*2 + 0)*16 + mrow + r)*16 + nn] = a00[r];
                part[((0*8 + (p*2+hl)*2 + 1)*16 + mrow + r)*16 + nn] = a01[r];
                part[((1*8 + (p*2+hl)*2 + 0)*16 + mrow + r)*16 + nn] = a10[r];
                part[((1*8 + (p*2+hl)*2 + 1)*16 + mrow + r)*16 + nn] = a11[r];
            }
        }
        __syncthreads();   // C: part-write -> gate-read

#pragma unroll
        for (int T = 0; T < 2; ++T) {
            float dot0 = 0.f, dot1 = 0.f, dot2 = 0.f, dot3 = 0.f;
            const float* wr = &w0l[(T*8 + ju)*4*48];
            const float* xr = &xsl[s&1][b*48];
#pragma unroll
            for (int k4 = 0; k4 < 40; k4 += 4) {
                float4 xk = *(const float4*)(xr + k4);
                float4 w0 = *(const float4*)(wr + 0*48 + k4);
                float4 w1 = *(const float4*)(wr + 1*48 + k4);
                float4 w2 = *(const float4*)(wr + 2*48 + k4);
                float4 w3 = *(const float4*)(wr + 3*48 + k4);
                dot0 += w0.x*xk.x + w0.y*xk.y + w0.z*xk.z + w0.w*xk.w;
                dot1 += w1.x*xk.x + w1.y*xk.y + w1.z*xk.z + w1.w*xk.w;
                dot2 += w2.x*xk.x + w2.y*xk.y + w2.z*xk.z + w2.w*xk.w;
                dot3 += w3.x*xk.x + w3.y*xk.y + w3.z*xk.z + w3.w*xk.w;
            }
            float xk = xr[40];
            dot0 += wr[0*48+40]*xk; dot1 += wr[1*48+40]*xk;
            dot2 += wr[2*48+40]*xk; dot3 += wr[3*48+40]*xk;
            float v[4] = {dot0, dot1, dot2, dot3};
#pragma unroll
            for (int g = 0; g < 4; ++g) {
                const int pp = g >> 1, m = (g & 1)*8 + ju;
                v[g] += part[((T*8 + (pp*2+0)*2 + nt)*16 + m)*16 + n]
                      + part[((T*8 + (pp*2+1)*2 + nt)*16 + m)*16 + n]
                      + biasr[T][g] + (float)t * wpos[T][g];
            }
            float ig = 1.f/(1.f + expf(-v[0]));
            float fg = 1.f/(1.f + expf(-v[1]));
            float gg = tanhf(v[2]);
            float og = 1.f/(1.f + expf(-v[3]));
            creg[T] = fg * creg[T] + ig * gg;
            hpk[T][b*8 + ju] = f2bf(og * tanhf(creg[T]));
        }
        __syncthreads();   // D: hpk-write -> pack-read

        // pack+store both T-chunks in parallel (r1 layout with ch2 = 2ch+T)
        if (tid < 128) {
            const int T = tid >> 6, tl = tid & 63;
            const int bb = tl >> 1, half = tl & 1;
            const u16* hp = &hpk[T][bb*8 + half*4];
            u64 pk = (u64)hp[0] | ((u64)hp[1]<<16) | ((u64)hp[2]<<32) | ((u64)hp[3]<<48);
            const int ch2 = ch*2 + T;
            const int ntb = bb >> 4, llb = ((ch2&3)<<4) | (bb&15);
            const int xoff = ((d*25 + (ch2>>2))*2 + ntb)*128 + llb*2 + half;
            astore((u64*)(h0f + (size_t)t*51200) + xoff, pk);
        }
        __syncthreads();   // E: drains vmcnt -> h at coherence point
        if (tid == 0) afstore(myflags + ch, s+1);
    }
}

// ---------------- Layer 1: r1-verbatim (persistent, 200 blocks) ----------------
__global__ __launch_bounds__(256, 1)
void lstm1_persist(const float* __restrict__ wih1, const float* __restrict__ whh1,
                   const float* __restrict__ bias, const float* __restrict__ lin_w,
                   const u16* __restrict__ h0f, u16* __restrict__ h1f,
                   int* __restrict__ flags, float* __restrict__ logits)
{
    __shared__ __align__(16) u16 wihL[2*50*512];        // 100 KB w_ih1 A-frags
    __shared__ __align__(16) u16 stageB[25600];         // 51.2 KB
    __shared__ __align__(16) float part[2048];          // 8 KB
    __shared__ u16 hpk[NB*8];
    const int tid = threadIdx.x;
    const int d = blockIdx.x / NCH, ch = blockIdx.x % NCH;
    const int w = tid >> 6, l = tid & 63;
    const int p = w & 1, hl = w >> 1;
    int* myflags = flags + d*128;

    short8 wreg[25];
    {
        const int m = l & 15, g = p*2 + (m>>3), j = ch*8 + (m&7);
        const float* base = whh1 + ((size_t)(d*G4_ + g*HID_ + j))*HID_ + (l>>4)*8;
#pragma unroll
        for (int kc = 0; kc < 25; ++kc) {
            float4 f0 = *(const float4*)(base + kc*32);
            float4 f1 = *(const float4*)(base + kc*32 + 4);
            short8 v;
            v[0]=cvt_hl(f0.x,hl); v[1]=cvt_hl(f0.y,hl); v[2]=cvt_hl(f0.z,hl); v[3]=cvt_hl(f0.w,hl);
            v[4]=cvt_hl(f1.x,hl); v[5]=cvt_hl(f1.y,hl); v[6]=cvt_hl(f1.z,hl); v[7]=cvt_hl(f1.w,hl);
            wreg[kc] = v;
        }
    }
    for (int o = tid; o < 6400; o += 256) {
        int pp = o / 3200, r = o % 3200, kc = r >> 6, ll = r & 63;
        int m = ll & 15, g = pp*2 + (m>>3), jj = ch*8 + (m&7);
        const float* base = wih1 + ((size_t)(d*G4_ + g*HID_ + jj))*IN1_ + kc*32 + (ll>>4)*8;
        float4 f0 = *(const float4*)base;
        float4 f1 = *(const float4*)(base + 4);
        short8 v;
        v[0]=(short)f2bf(f0.x); v[1]=(short)f2bf(f0.y); v[2]=(short)f2bf(f0.z); v[3]=(short)f2bf(f0.w);
        v[4]=(short)f2bf(f1.x); v[5]=(short)f2bf(f1.y); v[6]=(short)f2bf(f1.z); v[7]=(short)f2bf(f1.w);
        *(short8*)&wihL[o*8] = v;
    }
    // logit-owner constants + register-resident lin_w (step-invariant)
    const int ol = tid >> 5, ln = tid & 31;
    const int lo = ch*7 + ol;
    const bool lown = (ol < 7) && (lo < NB*NU);
    int lofs = 0;
    float wlin[25];
    if (lown) {
        const int bb = lo / NU, uu = lo % NU;
        lofs = (bb >> 4)*512 + ((((ln >> 3) << 4) | (bb & 15)))*8 + (ln & 7);
        const float* wrow = lin_w + (size_t)uu*IN1_ + d*HID_ + ln;
#pragma unroll
        for (int i = 0; i < 25; ++i) wlin[i] = wrow[i*32];
    }
    const int ju = tid >> 5, b = tid & 31;
    const int j = ch*8 + ju;
    const int nt = b >> 4, n = b & 15;
    float biasr[4];
#pragma unroll
    for (int g = 0; g < 4; ++g) biasr[g] = bias[d*G4_ + g*HID_ + j];
    float creg = 0.f;
    __syncthreads();

    for (int s = 0; s < T_LEN; ++s) {
        const int t = d ? (T_LEN-1-s) : s;

        // x-part GEMM BEFORE the poll: depends only on h0f (previous dispatch)
        f32x4 acc0 = {0.f,0.f,0.f,0.f}, acc1 = {0.f,0.f,0.f,0.f};
        {
            const u16* xb = h0f + (size_t)t*51200;
#pragma unroll 5
            for (int kc = 0; kc < 25; ++kc) {
                const int idx = hl*25 + kc;
                short8 a  = *(const short8*)&wihL[(p*50 + idx)*512 + l*8];
                short8 b0 = *(const short8*)(xb + idx*1024 + l*8);
                short8 b1 = *(const short8*)(xb + idx*1024 + 512 + l*8);
                acc0 = mfma16(a, b0, acc0);
                acc1 = mfma16(a, b1, acc1);
            }
        }

        if (s > 0 && tid < NCH)
            while (afload(myflags + tid) < s) __builtin_amdgcn_s_sleep(1);
        __syncthreads();

        if (s == 0) {
#pragma unroll
            for (int q = 0; q < 25; ++q) ((u64*)stageB)[tid + q*256] = 0ull;
        } else {
            const int tprev = d ? (T_LEN - s) : (s - 1);
            const u64* src = (const u64*)(h1f + (size_t)tprev*51200) + d*6400;
            u64 tmp[25];
#pragma unroll
            for (int q = 0; q < 25; ++q) tmp[q] = src[tid + q*256];
#pragma unroll
            for (int q = 0; q < 25; ++q) ((u64*)stageB)[tid + q*256] = tmp[q];
        }
        __syncthreads();

#pragma unroll 5
        for (int kc = 0; kc < 25; ++kc) {
            short8 b0 = *(const short8*)(stageB + kc*1024 + l*8);
            short8 b1 = *(const short8*)(stageB + kc*1024 + 512 + l*8);
            acc0 = mfma16(wreg[kc], b0, acc0);
            acc1 = mfma16(wreg[kc], b1, acc1);
        }
        {
            const int mrow = (l>>4)*4, nn = l & 15;
#pragma unroll
            for (int r = 0; r < 4; ++r) {
                part[(((p*2+hl)*2 + 0)*16 + mrow + r)*16 + nn] = acc0[r];
                part[(((p*2+hl)*2 + 1)*16 + mrow + r)*16 + nn] = acc1[r];
            }
        }
        __syncthreads();

        float v[4];
#pragma unroll
        for (int g = 0; g < 4; ++g) {
            const int pp = g >> 1, m = (g & 1)*8 + ju;
            v[g] = part[(((pp*2+0)*2 + nt)*16 + m)*16 + n]
                 + part[(((pp*2+1)*2 + nt)*16 + m)*16 + n] + biasr[g];
        }
        float ig = 1.f/(1.f + expf(-v[0]));
        float fg = 1.f/(1.f + expf(-v[1]));
        float gg = tanhf(v[2]);
        float og = 1.f/(1.f + expf(-v[3]));
        creg = fg * creg + ig * gg;
        float hn = og * tanhf(creg);
        hpk[b*8 + ju] = f2bf(hn);
        __syncthreads();

        if (tid < 64) {
            const int bb = tid >> 1, half = tid & 1;
            const u16* hp = &hpk[bb*8 + half*4];
            u64 pk = (u64)hp[0] | ((u64)hp[1]<<16) | ((u64)hp[2]<<32) | ((u64)hp[3]<<48);
            const int ntb = bb >> 4, llb = ((ch&3)<<4) | (bb&15);
            const int xoff = ((d*25 + (ch>>2))*2 + ntb)*128 + llb*2 + half;
            astore((u64*)(h1f + (size_t)t*51200) + xoff, pk);
        }
        __syncthreads();                       // drain h stores
        if (tid == 0) afstore(myflags + ch, s+1);

        // distributed logits for h(tprev) from stageB (valid until next staging)
        if (s > 0 && lown) {
            float sum = 0.f;
#pragma unroll
            for (int i = 0; i < 25; ++i)
                sum += bf2f(stageB[i*1024 + lofs]) * wlin[i];
#pragma unroll
            for (int off2 = 16; off2; off2 >>= 1) sum += __shfl_down(sum, off2, 32);
            if (ln == 0) {
                const int tprev = d ? (T_LEN - s) : (s - 1);
                logits[((size_t)d*T_LEN + tprev)*640 + lo] = sum;
            }
        }
    }
    // tail: logits for the final h
    if (tid < NCH)
        while (afload(myflags + tid) < T_LEN) __builtin_amdgcn_s_sleep(1);
    __syncthreads();
    {
        const int tlast = d ? 0 : (T_LEN - 1);
        const u64* src = (const u64*)(h1f + (size_t)tlast*51200) + d*6400;
        u64 tmp[25];
#pragma unroll
        for (int q = 0; q < 25; ++q) tmp[q] = src[tid + q*256];
#pragma unroll
        for (int q = 0; q < 25; ++q) ((u64*)stageB)[tid + q*256] = tmp[q];
    }
    __syncthreads();
    if (lown) {
        float sum = 0.f;
#pragma unroll
        for (int i = 0; i < 25; ++i)
            sum += bf2f(stageB[i*1024 + lofs]) * wlin[i];
#pragma unroll
        for (int off2 = 16; off2; off2 >>= 1) sum += __shfl_down(sum, off2, 32);
        if (ln == 0) {
            const int tprev = d ? 0 : (T_LEN - 1);
            logits[((size_t)d*T_LEN + tprev)*640 + lo] = sum;
        }
    }
}

// ---- sum dirs + lin_b -> softmax -> alphabet sin/cos mix; store (cosP, sinP) ----
__global__ __launch_bounds__(256)
void epilogue(const float* __restrict__ logits, const float* __restrict__ lin_b,
              const float* __restrict__ alphabet, float* __restrict__ cs)
{
    __shared__ float sa[NU*3], ca[NU*3], lb[NU];
    const int tid = threadIdx.x;
    if (tid < NU*3) { float al = alphabet[tid]; sa[tid] = sinf(al); ca[tid] = cosf(al); }
    if (tid < NU) lb[tid] = lin_b[tid];
    __syncthreads();
    const int row = blockIdx.x*256 + tid;   // t*NB + b
    if (row >= T_LEN*NB) return;
    const int t = row >> 5, b = row & 31;
    float lg[NU];
    float m = -1e30f;
#pragma unroll 4
    for (int u = 0; u < NU; ++u) {
        lg[u] = lb[u] + logits[(size_t)t*640 + b*NU + u]
                      + logits[((size_t)T_LEN + t)*640 + b*NU + u];
        m = fmaxf(m, lg[u]);
    }
    float ssum = 0.f;
#pragma unroll 4
    for (int u = 0; u < NU; ++u) { lg[u] = expf(lg[u] - m); ssum += lg[u]; }
    float inv = 1.f / ssum;
#pragma unroll
    for (int i = 0; i < 3; ++i) {
        float sv = 0.f, cv = 0.f;
#pragma unroll 4
        for (int u = 0; u < NU; ++u) {
            float sw = lg[u] * inv;
            sv += sw * sa[u*3 + i];
            cv += sw * ca[u*3 + i];
        }
        float rinv = rsqrtf(fmaxf(sv*sv + cv*cv, 1e-30f));
        *(float2*)(cs + ((size_t)row*3 + i)*2) = make_float2(cv*rinv, sv*rinv);
    }
}

// ---- sequential chain extension: one lane per molecule ----
__global__ __launch_bounds__(64)
void geometry(const float* __restrict__ cs, float* __restrict__ out)
{
    const int b = threadIdx.x;
    if (b >= NB) return;
    const float blen[3] = {1.329f, 1.459f, 1.525f};
    const float bang[3] = {2.034f, 2.119f, 1.937f};
    float sT[3], cT[3];
#pragma unroll
    for (int i = 0; i < 3; ++i) { sT[i] = sinf(bang[i]); cT[i] = cosf(bang[i]); }

    float Ax=0.f,Ay=0.f,Az=1.f, Bx=0.f,By=1.f,Bz=0.f, Cx=1.f,Cy=0.f,Cz=0.f;
    out[(0*NB + b)*3 + 0] = 0.f; out[(0*NB + b)*3 + 1] = 0.f; out[(0*NB + b)*3 + 2] = 1.f;
    out[(1*NB + b)*3 + 0] = 0.f; out[(1*NB + b)*3 + 1] = 1.f; out[(1*NB + b)*3 + 2] = 0.f;
    out[(2*NB + b)*3 + 0] = 1.f; out[(2*NB + b)*3 + 1] = 0.f; out[(2*NB + b)*3 + 2] = 0.f;

    for (int t = 1; t < T_LEN; ++t) {
        float2 pc[3];
#pragma unroll
        for (int i = 0; i < 3; ++i)
            pc[i] = *(const float2*)(cs + (((size_t)t*NB + b)*3 + i)*2);
#pragma unroll
        for (int i = 0; i < 3; ++i) {
            float R = blen[i];
            float d2x = -R*cT[i], d2y = R*pc[i].x*sT[i], d2z = R*pc[i].y*sT[i];
            float bcx = Cx-Bx, bcy = Cy-By, bcz = Cz-Bz;
            float inv = rsqrtf(bcx*bcx + bcy*bcy + bcz*bcz);
            bcx *= inv; bcy *= inv; bcz *= inv;
            float abx = Bx-Ax, aby = By-Ay, abz = Bz-Az;
            float nx = aby*bcz - abz*bcy;
            float ny = abz*bcx - abx*bcz;
            float nz = abx*bcy - aby*bcx;
            inv = rsqrtf(fmaxf(nx*nx + ny*ny + nz*nz, 1e-30f));
            nx *= inv; ny *= inv; nz *= inv;
            float mx = ny*bcz - nz*bcy;
            float my = nz*bcx - nx*bcz;
            float mz = nx*bcy - ny*bcx;
            float Dx = bcx*d2x + mx*d2y + nx*d2z + Cx;
            float Dy = bcy*d2x + my*d2y + ny*d2z + Cy;
            float Dz = bcz*d2x + mz*d2y + nz*d2z + Cz;
            Ax=Bx; Ay=By; Az=Bz; Bx=Cx; By=Cy; Bz=Cz; Cx=Dx; Cy=Dy; Cz=Dz;
            const int r = 3 + (t-1)*3 + i;
            out[((size_t)r*NB + b)*3 + 0] = Dx;
            out[((size_t)r*NB + b)*3 + 1] = Dy;
            out[((size_t)r*NB + b)*3 + 2] = Dz;
        }
    }
}

extern "C" void kernel_launch(void* const* d_in, const int* in_sizes, int n_in,
                              void* d_out, int out_size, void* d_ws, size_t ws_size,
                              hipStream_t stream)
{
    (void)in_sizes; (void)n_in; (void)out_size; (void)ws_size;
    const float* seq   = (const float*)d_in[0];
    const float* w_ih0 = (const float*)d_in[2];
    const float* w_hh0 = (const float*)d_in[3];
    const float* b0    = (const float*)d_in[4];
    const float* w_ih1 = (const float*)d_in[5];
    const float* w_hh1 = (const float*)d_in[6];
    const float* b1    = (const float*)d_in[7];
    const float* lin_w = (const float*)d_in[8];
    const float* lin_b = (const float*)d_in[9];
    const float* alpha = (const float*)d_in[10];

    // workspace (~107.9 MB): two per-timestep h rings + packed flags
    char* ws = (char*)d_ws;
    size_t off = 0;
    u16* h0f   = (u16*)(ws + off); off += 52428800ull;   // [t][d][kc25][nt2][lane][i] bf16
    u16* h1f   = (u16*)(ws + off); off += 52428800ull;   // layer-1 per-t ring
    int* flagsL0 = (int*)(ws + off); off += 1024ull;     // 2 dirs x 128 ints (packed 4B)
    int* flagsL1 = (int*)(ws + off); off += 1024ull;
    float* logits = (float*)(ws + off); off += 2621440ull;
    float* cs = (float*)(ws + off); off += 393216ull;

    hipMemsetAsync(flagsL0, 0, 2048, stream);   // both flag arrays

    lstm0_persist<<<dim3(2*NCH0), dim3(256), 0, stream>>>(seq, w_ih0, w_hh0, b0, h0f, flagsL0);

    lstm1_persist<<<dim3(2*NCH), dim3(256), 0, stream>>>(w_ih1, w_hh1, b1, lin_w, h0f, h1f,
                                                         flagsL1, logits);

    epilogue<<<dim3(64), dim3(256), 0, stream>>>(logits, lin_b, alpha, cs);
    geometry<<<dim3(1), dim3(64), 0, stream>>>(cs, (float*)d_out);
}